// Round 11
// baseline (1595.493 us; speedup 1.0000x reference)
//
#include <hip/hip_runtime.h>

// NTM controller B=64,T=512,I=64,H=256,O=64. Memory module provably dead
// (mem0=0 -> lw=0 -> add=tanh(0)=0 -> mem stays 0, read_vec=0):
//   LSTM recurrence + out = h @ W_dec[:, :256]^T + b_dec.
//
// Round-10 diagnosis: LDS RETURN bandwidth bound (409 KB/step: 147 KB weights +
// 262 KB h-broadcast -- every wave re-reads all 256 h per lane). Fix: k-split-4.
// rec: 64 blocks x 512 thr. Thread (n=tid>>2, m=tid&3) owns 8 rows = gates
// {i,f,g,o} x units {n, n+128}, k-window [64m,64m+64). Per row (32 f16x2 pairs):
//   pairs  0..7   -> VGPRs (8x8 = 64 regs)
//   pairs  8..23  -> AGPRs (8x16 = 128, full acc file; non-volatile batched reads)
//   pairs 24..31  -> LDS [16][512] uint4 (131072 B, 16 B/lane conflict-free)
// h traffic: 8 quads/thread (64 KB/step vs 262). k-reduction: 2-round shfl_xor
// butterfly over the 4-lane group; xp added ONCE post-butterfly; LSTM computed
// redundantly in 4 lanes (bit-identical: commutative adds). One barrier/step.
// Phase 1 (xproj): XPh[b][t][unit][4] f16 = x@W_ih^T + b_ih + b_hh (i,f,g,o).
// Phase 3 (dec):   out[b,t,:] = H[b,t,:] @ W_dec[:, :256]^T + b_dec.

typedef _Float16 f16x2 __attribute__((ext_vector_type(2)));

#define NB   64
#define TT   512
#define XP_BYTES  (67108864u)   // 64*512*1024*2
#define HD_BYTES  (16777216u)   // 64*512*256*2

__device__ unsigned char g_ntm_ws[XP_BYTES + HD_BYTES];  // fallback workspace

union U32H { unsigned int u; f16x2 h; };
union USH  { _Float16 f; unsigned short u; };
static __device__ __forceinline__ unsigned int pack2f(float a, float b) {
    U32H v; v.h = f16x2{(_Float16)a, (_Float16)b}; return v.u;
}
static __device__ __forceinline__ f16x2 up(unsigned int u) { U32H v; v.u = u; return v.h; }
static __device__ __forceinline__ unsigned short f2s(float a) { USH v; v.f = (_Float16)a; return v.u; }

__device__ __forceinline__ float sigf(float x) { return 1.0f / (1.0f + __expf(-x)); }
__device__ __forceinline__ float tanhfast(float x) {
    float e = __expf(2.0f * x);
    return 1.0f - 2.0f / (e + 1.0f);
}

#if __has_builtin(__builtin_amdgcn_fdot2)
__device__ __forceinline__ float dot2(f16x2 a, f16x2 b, float c) {
    return __builtin_amdgcn_fdot2(a, b, c, false);
}
#else
__device__ __forceinline__ float dot2(f16x2 a, f16x2 b, float c) {
    return c + (float)a.x * (float)b.x + (float)a.y * (float)b.y;
}
#endif

// ---------------- phase 1: x-projection ----------------
// XPh[b][t][unit g][r] f16, r=0:i,1:f,2:g,3:o. Thread tid handles rows tid, tid+512.
__global__ void __attribute__((amdgpu_flat_work_group_size(512, 512)))
xproj_kernel(const float* __restrict__ x_seq, const float* __restrict__ W_ih,
             const float* __restrict__ b_ih, const float* __restrict__ b_hh,
             unsigned short* XPh)
{
    if (!XPh) XPh = (unsigned short*)g_ntm_ws;
    __shared__ unsigned int xq[128 * 32];     // 16 KB: 128 t-rows of x, f16 pairs
    const int tid = threadIdx.x;
    const int b   = blockIdx.x >> 2;
    const int q   = blockIdx.x & 3;

    {   // stage x chunk
        const float* src = x_seq + ((size_t)b * TT + (size_t)q * 128 + (tid >> 2)) * 64
                         + (tid & 3) * 16;
        unsigned int* dst = xq + (tid >> 2) * 32 + (tid & 3) * 8;
#pragma unroll
        for (int i = 0; i < 4; ++i) {
            float4 v = ((const float4*)src)[i];
            dst[2 * i]     = pack2f(v.x, v.y);
            dst[2 * i + 1] = pack2f(v.z, v.w);
        }
    }

    unsigned int w0p[32], w1p[32];            // rows tid, tid+512 as f16 pairs
    {
        const float* r0 = W_ih + (size_t)tid * 64;
        const float* r1 = W_ih + (size_t)(tid + 512) * 64;
#pragma unroll
        for (int i = 0; i < 16; ++i) {
            float4 v0 = *(const float4*)(r0 + 4 * i);
            float4 v1 = *(const float4*)(r1 + 4 * i);
            w0p[2*i] = pack2f(v0.x, v0.y); w0p[2*i+1] = pack2f(v0.z, v0.w);
            w1p[2*i] = pack2f(v1.x, v1.y); w1p[2*i+1] = pack2f(v1.z, v1.w);
        }
    }
    const float bias0 = b_ih[tid]       + b_hh[tid];
    const float bias1 = b_ih[tid + 512] + b_hh[tid + 512];
    const int   g4A   = (tid & 255) * 4 + ((tid < 256) ? 0 : 1);   // row tid -> gate i or f
    __syncthreads();

    unsigned short* outh = XPh + ((size_t)b * TT + (size_t)q * 128) * 1024;
    for (int tt = 0; tt < 128; ++tt) {
        const uint4* xr = (const uint4*)(xq + tt * 32);
        float a0 = bias0, a1 = bias1;
        float a2 = 0.f, a3 = 0.f, a4 = 0.f, a5 = 0.f, a6 = 0.f, a7 = 0.f;
#pragma unroll
        for (int i = 0; i < 8; ++i) {
            uint4 xv = xr[i];
            a0 = dot2(up(w0p[4*i]),   up(xv.x), a0);  a1 = dot2(up(w1p[4*i]),   up(xv.x), a1);
            a2 = dot2(up(w0p[4*i+1]), up(xv.y), a2);  a3 = dot2(up(w1p[4*i+1]), up(xv.y), a3);
            a4 = dot2(up(w0p[4*i+2]), up(xv.z), a4);  a5 = dot2(up(w1p[4*i+2]), up(xv.z), a5);
            a6 = dot2(up(w0p[4*i+3]), up(xv.w), a6);  a7 = dot2(up(w1p[4*i+3]), up(xv.w), a7);
        }
        const float gA = (a0 + a2) + (a4 + a6);   // row tid
        const float gB = (a1 + a3) + (a5 + a7);   // row tid+512
        outh[tt * 1024 + g4A]     = f2s(gA);
        outh[tt * 1024 + g4A + 2] = f2s(gB);      // row tid+512 = gate r+2 of same unit
    }
}

// ---------------- phase 2: recurrence ----------------
// LDS: wl4 uint4[16][512] (131072 B) | h16 _Float16[2][256] (1024 B)
__global__ void
__attribute__((amdgpu_flat_work_group_size(512, 512), amdgpu_waves_per_eu(2, 2)))
ntm_rec(const float* __restrict__ W_hh,
        const unsigned short* __restrict__ XPh_in,
        unsigned short* __restrict__ Hd_in)
{
    extern __shared__ char smem[];
    uint4*    wl4 = (uint4*)smem;                         // [16][512]
    _Float16* h16 = (_Float16*)(smem + 16 * 512 * 16);    // [2][256]

    const unsigned short* XPh = XPh_in ? XPh_in : (const unsigned short*)g_ntm_ws;
    unsigned short*       Hd  = Hd_in  ? Hd_in  : (unsigned short*)(g_ntm_ws + XP_BYTES);

    const int tid = threadIdx.x;
    const int b   = blockIdx.x;
    const int n   = tid >> 2;        // unit-group: owns units n and n+128
    const int m   = tid & 3;         // k-window index: k in [64m, 64m+64)

    // ---- weights: 8 rows k=(j*4+r): gate r of unit n+128j, window [64m,64m+64) ----
    f16x2 wv[8][8];                  // pairs 0..7 of each row (64 VGPRs)
    unsigned int wag[128];           // pairs 8..23 of each row -> AGPRs
#pragma unroll
    for (int k = 0; k < 8; ++k) {
        const int row = 256 * (k & 3) + n + 128 * (k >> 2);
        const float* rp = W_hh + (size_t)row * 256 + 64 * m;
#pragma unroll
        for (int p = 0; p < 8; ++p) {            // pairs 0..7 -> VGPR
            float2 v = *(const float2*)(rp + 2 * p);
            wv[k][p] = f16x2{(_Float16)v.x, (_Float16)v.y};
        }
#pragma unroll
        for (int p = 0; p < 16; ++p) {           // pairs 8..23 -> AGPR
            float2 v = *(const float2*)(rp + 16 + 2 * p);
            unsigned int u = pack2f(v.x, v.y);
            asm volatile("v_accvgpr_write_b32 %0, %1" : "=a"(wag[k * 16 + p]) : "v"(u));
        }
        // pairs 24..31 -> LDS: two uint4 per row
        const float* s0 = rp + 48;
        wl4[(2 * k)     * 512 + tid] = make_uint4(pack2f(s0[0],  s0[1]),  pack2f(s0[2],  s0[3]),
                                                  pack2f(s0[4],  s0[5]),  pack2f(s0[6],  s0[7]));
        wl4[(2 * k + 1) * 512 + tid] = make_uint4(pack2f(s0[8],  s0[9]),  pack2f(s0[10], s0[11]),
                                                  pack2f(s0[12], s0[13]), pack2f(s0[14], s0[15]));
    }

    if (tid < 64) ((uint4*)h16)[tid] = make_uint4(0u, 0u, 0u, 0u);   // both h buffers = 0
    float c0 = 0.f, c1 = 0.f;        // c for units n, n+128
    __syncthreads();

    const uint2* xpb = (const uint2*)XPh + (size_t)b * TT * 256;     // [t][unit] (i,f | g,o)
    uint4*       Hd4 = (uint4*)Hd + (size_t)b * TT * 32;

    uint2 xc0 = xpb[n];              // t=0, unit n
    uint2 xc1 = xpb[n + 128];        // t=0, unit n+128

    for (int t = 0; t < TT; ++t) {
        const uint4* hq = (const uint4*)(h16 + (t & 1) * 256) + 8 * m;  // my k-window
        uint2 xn0 = xc0, xn1 = xc1;
        if (t + 1 < TT) {                                            // prefetch t+1
            xn0 = xpb[(size_t)(t + 1) * 256 + n];
            xn1 = xpb[(size_t)(t + 1) * 256 + n + 128];
        }

        float a[8];
#pragma unroll
        for (int k = 0; k < 8; ++k) a[k] = 0.f;

        // ---- quads 0..1: VGPR pairs 0..7 ----
#pragma unroll
        for (int i = 0; i < 2; ++i) {
            const uint4 hv = hq[i];
#pragma unroll
            for (int k = 0; k < 8; ++k) {
                a[k] = dot2(wv[k][4*i],   up(hv.x), a[k]);
                a[k] = dot2(wv[k][4*i+1], up(hv.y), a[k]);
                a[k] = dot2(wv[k][4*i+2], up(hv.z), a[k]);
                a[k] = dot2(wv[k][4*i+3], up(hv.w), a[k]);
            }
        }
        // ---- quads 2..5: AGPR pairs 8..23 (batched non-volatile reads) ----
#pragma unroll
        for (int i = 0; i < 4; ++i) {
            const uint4 hv = hq[2 + i];
#pragma unroll
            for (int p = 0; p < 4; ++p) {
                const unsigned int hp = (p == 0) ? hv.x : (p == 1) ? hv.y
                                      : (p == 2) ? hv.z : hv.w;
                unsigned int tw[8];
#pragma unroll
                for (int k = 0; k < 8; ++k)
                    asm("v_accvgpr_read_b32 %0, %1" : "=v"(tw[k]) : "a"(wag[k*16 + 4*i + p]));
#pragma unroll
                for (int k = 0; k < 8; ++k)
                    a[k] = dot2(up(tw[k]), up(hp), a[k]);
            }
        }
        // ---- quads 6..7: LDS pairs 24..31 ----
#pragma unroll
        for (int i = 0; i < 2; ++i) {
            const uint4 hv = hq[6 + i];
#pragma unroll
            for (int k = 0; k < 8; ++k) {
                const uint4 wq = wl4[(2 * k + i) * 512 + tid];
                a[k] = dot2(up(wq.x), up(hv.x), a[k]);
                a[k] = dot2(up(wq.y), up(hv.y), a[k]);
                a[k] = dot2(up(wq.z), up(hv.z), a[k]);
                a[k] = dot2(up(wq.w), up(hv.w), a[k]);
            }
        }

        // ---- butterfly over 4-lane group: sum the k-windows (commutative ->
        // bit-identical in all 4 lanes) ----
#pragma unroll
        for (int k = 0; k < 8; ++k) {
            a[k] += __shfl_xor(a[k], 1);
            a[k] += __shfl_xor(a[k], 2);
        }

        // ---- x-projection (+biases) added ONCE post-reduction; LSTM x2 units ----
        {
            const f16x2 lo = up(xc0.x), hi = up(xc0.y);   // unit n: (i,f),(g,o)
            const float gi = a[0] + (float)lo.x;
            const float gf = a[1] + (float)lo.y;
            const float gg = a[2] + (float)hi.x;
            const float go = a[3] + (float)hi.y;
            c0 = sigf(gf) * c0 + sigf(gi) * tanhfast(gg);
            const float hn = sigf(go) * tanhfast(c0);
            if (m == 0) (h16 + (((t + 1) & 1) << 8))[n] = (_Float16)hn;
        }
        {
            const f16x2 lo = up(xc1.x), hi = up(xc1.y);   // unit n+128
            const float gi = a[4] + (float)lo.x;
            const float gf = a[5] + (float)lo.y;
            const float gg = a[6] + (float)hi.x;
            const float go = a[7] + (float)hi.y;
            c1 = sigf(gf) * c1 + sigf(gi) * tanhfast(gg);
            const float hn = sigf(go) * tanhfast(c1);
            if (m == 0) (h16 + (((t + 1) & 1) << 8))[n + 128] = (_Float16)hn;
        }
        __syncthreads();                                             // h_t published
        if (tid < 32)
            Hd4[(size_t)t * 32 + tid] = ((const uint4*)(h16 + (((t + 1) & 1) << 8)))[tid];
        xc0 = xn0; xc1 = xn1;
    }
}

// ---------------- phase 3: decode ----------------
// out[b,t,o] = b_dec[o] + H[b,t,:256] . W_dec[o,:256]
__global__ void __attribute__((amdgpu_flat_work_group_size(256, 256)))
dec_kernel(const unsigned short* __restrict__ Hd_in,
           const float* __restrict__ W_dec, const float* __restrict__ b_dec,
           float* __restrict__ out)
{
    const unsigned short* Hd = Hd_in ? Hd_in : (const unsigned short*)(g_ntm_ws + XP_BYTES);
    __shared__ unsigned int wdl[64 * 132];    // W_dec pairs, padded stride 132
    __shared__ uint4 ht[32 * 32];             // 32 t-rows x 256 f16

    const int tid = threadIdx.x;
    const int b = blockIdx.x >> 2, q = blockIdx.x & 3;

    for (int idx = tid; idx < 64 * 128; idx += 256) {
        const int o = idx >> 7, pp = idx & 127;
        wdl[o * 132 + pp] = pack2f(W_dec[(size_t)o * 384 + 2 * pp],
                                   W_dec[(size_t)o * 384 + 2 * pp + 1]);
    }
    const int o = tid & 63, tq = tid >> 6;
    const float bd = b_dec[o];
    const uint4* Hdb  = (const uint4*)Hd + ((size_t)b * TT + (size_t)q * 128) * 32;
    float*       outb = out + ((size_t)b * TT + (size_t)q * 128) * 64;

    for (int s = 0; s < 4; ++s) {
        __syncthreads();
#pragma unroll
        for (int i = 0; i < 4; ++i) {
            const int idx = tid + 256 * i;                 // 1024 uint4 = 32 rows
            ht[idx] = Hdb[s * 1024 + idx];
        }
        __syncthreads();

        float acc[8];
#pragma unroll
        for (int j = 0; j < 8; ++j) acc[j] = 0.f;

#pragma unroll
        for (int c = 0; c < 8; ++c) {                      // k-chunks of 32 slices
            uint4 w0, w1, w2, w3;
            {
                const unsigned int* wp = wdl + o * 132 + 16 * c;
                w0 = make_uint4(wp[0],  wp[1],  wp[2],  wp[3]);
                w1 = make_uint4(wp[4],  wp[5],  wp[6],  wp[7]);
                w2 = make_uint4(wp[8],  wp[9],  wp[10], wp[11]);
                w3 = make_uint4(wp[12], wp[13], wp[14], wp[15]);
            }
#pragma unroll
            for (int j = 0; j < 8; ++j) {
                const uint4* hr = &ht[(tq * 8 + j) * 32 + 4 * c];
                const uint4 h0 = hr[0], h1 = hr[1], h2 = hr[2], h3 = hr[3];
                float d = acc[j];
                d = dot2(up(w0.x), up(h0.x), d); d = dot2(up(w0.y), up(h0.y), d);
                d = dot2(up(w0.z), up(h0.z), d); d = dot2(up(w0.w), up(h0.w), d);
                d = dot2(up(w1.x), up(h1.x), d); d = dot2(up(w1.y), up(h1.y), d);
                d = dot2(up(w1.z), up(h1.z), d); d = dot2(up(w1.w), up(h1.w), d);
                d = dot2(up(w2.x), up(h2.x), d); d = dot2(up(w2.y), up(h2.y), d);
                d = dot2(up(w2.z), up(h2.z), d); d = dot2(up(w2.w), up(h2.w), d);
                d = dot2(up(w3.x), up(h3.x), d); d = dot2(up(w3.y), up(h3.y), d);
                d = dot2(up(w3.z), up(h3.z), d); d = dot2(up(w3.w), up(h3.w), d);
                acc[j] = d;
            }
        }
#pragma unroll
        for (int j = 0; j < 8; ++j)
            outb[(size_t)(s * 32 + tq * 8 + j) * 64 + o] = acc[j] + bd;
    }
}

extern "C" void kernel_launch(void* const* d_in, const int* in_sizes, int n_in,
                              void* d_out, int out_size, void* d_ws, size_t ws_size,
                              hipStream_t stream) {
    const float* x_seq = (const float*)d_in[0];
    const float* W_ih  = (const float*)d_in[1];
    const float* W_hh  = (const float*)d_in[2];
    const float* b_ih  = (const float*)d_in[3];
    const float* b_hh  = (const float*)d_in[4];
    // d_in[5..8] unused: mem == 0 forever
    const float* W_dec = (const float*)d_in[9];
    const float* b_dec = (const float*)d_in[10];
    float* out = (float*)d_out;

    unsigned short* XPh = nullptr;   // null -> kernels fall back to g_ntm_ws
    unsigned short* Hd  = nullptr;
    if (ws_size >= (size_t)XP_BYTES + HD_BYTES) {
        XPh = (unsigned short*)d_ws;
        Hd  = (unsigned short*)((unsigned char*)d_ws + XP_BYTES);
    }

    hipLaunchKernelGGL(xproj_kernel, dim3(256), dim3(512), 0, stream,
                       x_seq, W_ih, b_ih, b_hh, XPh);

    const size_t smem_rec = (size_t)16 * 512 * 16 + 1024;   // 132096 B
    hipFuncSetAttribute((const void*)&ntm_rec,
                        hipFuncAttributeMaxDynamicSharedMemorySize, (int)smem_rec);
    hipLaunchKernelGGL(ntm_rec, dim3(NB), dim3(512), smem_rec, stream,
                       W_hh, XPh, Hd);

    hipLaunchKernelGGL(dec_kernel, dim3(256), dim3(256), 0, stream,
                       Hd, W_dec, b_dec, out);
}